// Round 2
// baseline (119.621 us; speedup 1.0000x reference)
//
#include <hip/hip_runtime.h>

#define H 1024
#define W 1024
#define NC 12   // channels
#define ND 8    // depth
#define HG 16
#define WG 16
#define ROWS 2      // y-rows per block
#define PX 2        // pixels per thread
#define HALFW 512   // pixels per block in x (256 threads * PX)
#define XPITCH 100  // dwords per x-cell in LDS (96 data + 4 pad -> bank decorrelation)

// One block per (x-half, y-pair, n). y-interp folded into LDS staging.
// LDS layout sg[r][x*XPITCH + z*NC + c]: x-stride 100 dwords so bank =
// (4*x + 12*z + c) % 32 -- x-cells no longer alias to the same banks
// (old stride 96 == 0 mod 32 was a ~4-way read / 16-way write conflict).
// 2 px/thread + launch_bounds(256,6) targets 24 waves/CU for latency hiding.
__global__ __launch_bounds__(256, 6) void slice_kernel(
    const float* __restrict__ grid,
    const float* __restrict__ guide,
    float* __restrict__ out)
{
    const int xh  = blockIdx.x & 1;          // x half
    const int yp  = blockIdx.x >> 1;         // y pair
    const int n   = blockIdx.y;
    const int y0  = yp * ROWS;
    const int tid = threadIdx.x;
    const int xb  = xh * HALFW + tid * PX;   // first of PX consecutive pixels

    // ---- Early guide loads (cold HBM) — overlap with LDS staging below.
    const float* gd = guide + ((size_t)n * H + y0) * W;
    float2 g2[ROWS];
    g2[0] = *(const float2*)&gd[xb];
    g2[1] = *(const float2*)&gd[W + xb];

    // ---- Stage ROWS y-interpolated grid slices into LDS (padded layout).
    __shared__ __align__(16) float sg[ROWS][WG * XPITCH];
    const float* gbase = grid + (size_t)n * NC * ND * HG * WG;

    #pragma unroll
    for (int r = 0; r < ROWS; ++r) {
        const int y = y0 + r;
        float yn = -1.0f + (float)y * (2.0f / (float)(H - 1));
        float iy = (yn + 1.0f) * 0.5f * (float)(HG - 1);
        iy = fminf(fmaxf(iy, 0.0f), (float)(HG - 1));
        int   iy0 = (int)floorf(iy);
        int   iy1 = min(iy0 + 1, HG - 1);
        float wy  = iy - (float)iy0;

        #pragma unroll
        for (int k = 0; k < (WG * ND * NC) / 256; ++k) {
            int i  = tid + k * 256;
            int x  = i & (WG - 1);
            int zc = i >> 4;
            int z  = zc & (ND - 1);
            int c  = zc >> 3;
            const float* gp = gbase + ((c * ND + z) * HG) * WG + x;
            float r0 = gp[iy0 * WG];
            float r1 = gp[iy1 * WG];
            sg[r][x * XPITCH + z * NC + c] = r0 + (r1 - r0) * wy;
        }
    }

    // ---- Per-pixel x-setup (row-independent), before the barrier.
    int   B0[PX], B1[PX];
    float wxv[PX];
    #pragma unroll
    for (int p = 0; p < PX; ++p) {
        const int x = xb + p;
        float xn = -1.0f + (float)x * (2.0f / (float)(W - 1));
        float ix = (xn + 1.0f) * 0.5f * (float)(WG - 1);
        ix = fminf(fmaxf(ix, 0.0f), (float)(WG - 1));
        int   ix0 = (int)floorf(ix);
        int   ix1 = min(ix0 + 1, WG - 1);
        wxv[p] = ix - (float)ix0;
        B0[p]  = ix0 * XPITCH;
        B1[p]  = ix1 * XPITCH;
    }

    __syncthreads();

    float* ob = out + (size_t)n * NC * H * W + (size_t)y0 * W + xb;

    #pragma unroll
    for (int r = 0; r < ROWS; ++r) {
        const float gz[PX] = { g2[r].x, g2[r].y };

        // Per-pixel corner addresses + bilinear (x,z) weights for this row.
        int   A00[PX], A01[PX], A10[PX], A11[PX];
        float w00[PX], w01[PX], w10[PX], w11[PX];
        #pragma unroll
        for (int p = 0; p < PX; ++p) {
            float zn = gz[p] * 2.0f - 1.0f;
            float iz = (zn + 1.0f) * 0.5f * (float)(ND - 1);
            iz = fminf(fmaxf(iz, 0.0f), (float)(ND - 1));
            int   iz0 = (int)floorf(iz);
            int   iz1 = min(iz0 + 1, ND - 1);
            float wz  = iz - (float)iz0;

            const int Z0 = iz0 * NC;
            const int Z1 = iz1 * NC;
            A00[p] = B0[p] + Z0;  A01[p] = B0[p] + Z1;
            A10[p] = B1[p] + Z0;  A11[p] = B1[p] + Z1;

            const float wx = wxv[p];
            const float ux = 1.0f - wx;
            const float uz = 1.0f - wz;
            w00[p] = ux * uz;  w01[p] = ux * wz;
            w10[p] = wx * uz;  w11[p] = wx * wz;
        }

        #pragma unroll
        for (int cc = 0; cc < NC; cc += 4) {
            float4 q[PX];
            #pragma unroll
            for (int p = 0; p < PX; ++p) {
                const float4 a0 = *(const float4*)&sg[r][A00[p] + cc];
                const float4 a1 = *(const float4*)&sg[r][A01[p] + cc];
                const float4 b0 = *(const float4*)&sg[r][A10[p] + cc];
                const float4 b1 = *(const float4*)&sg[r][A11[p] + cc];
                const float k00 = w00[p], k01 = w01[p], k10 = w10[p], k11 = w11[p];
                q[p].x = a0.x * k00 + a1.x * k01 + b0.x * k10 + b1.x * k11;
                q[p].y = a0.y * k00 + a1.y * k01 + b0.y * k10 + b1.y * k11;
                q[p].z = a0.z * k00 + a1.z * k01 + b0.z * k10 + b1.z * k11;
                q[p].w = a0.w * k00 + a1.w * k01 + b0.w * k10 + b1.w * k11;
            }
            {
                float2 v;
                v = make_float2(q[0].x, q[1].x);
                *(float2*)&ob[(size_t)(cc + 0) * H * W + (size_t)r * W] = v;
                v = make_float2(q[0].y, q[1].y);
                *(float2*)&ob[(size_t)(cc + 1) * H * W + (size_t)r * W] = v;
                v = make_float2(q[0].z, q[1].z);
                *(float2*)&ob[(size_t)(cc + 2) * H * W + (size_t)r * W] = v;
                v = make_float2(q[0].w, q[1].w);
                *(float2*)&ob[(size_t)(cc + 3) * H * W + (size_t)r * W] = v;
            }
        }
    }
}

extern "C" void kernel_launch(void* const* d_in, const int* in_sizes, int n_in,
                              void* d_out, int out_size, void* d_ws, size_t ws_size,
                              hipStream_t stream) {
    const float* grid  = (const float*)d_in[0];
    const float* guide = (const float*)d_in[1];
    float* out = (float*)d_out;

    dim3 grd((W / HALFW) * (H / ROWS), 2);   // (x-half * y-pair, n) = 1024 x 2
    dim3 blk(256);
    slice_kernel<<<grd, blk, 0, stream>>>(grid, guide, out);
}